// Round 1
// baseline (782.521 us; speedup 1.0000x reference)
//
#include <hip/hip_runtime.h>
#include <cstdint>
#include <cstddef>

#define IN_CH 256
#define OUT_CH 128
#define NEG_SLOPE 0.2f
#define EPS 1e-16f

// ---------------- GEMM (xp = x @ W) + alpha epilogue ----------------
#define BM 64
#define BN 128
#define BK 32

__global__ __launch_bounds__(256) void gemm_alpha_kernel(
    const float* __restrict__ x, const float* __restrict__ w,
    const float* __restrict__ att_s, const float* __restrict__ att_d,
    float* __restrict__ xp, float* __restrict__ asrc, float* __restrict__ adst,
    int M)
{
    __shared__ float sA[BK][BM + 4];   // [k][m], +4 pad keeps float4 alignment
    __shared__ float sB[BK][BN];       // [k][n]
    const int tid = threadIdx.x;
    const int ty = tid >> 4;           // 0..15 : row group (4 rows each)
    const int tx = tid & 15;           // 0..15 : col group (8 cols each)
    const int row0 = blockIdx.x * BM;

    float acc[4][8];
#pragma unroll
    for (int i = 0; i < 4; ++i)
#pragma unroll
        for (int j = 0; j < 8; ++j) acc[i][j] = 0.f;

    const int ar = tid >> 2;           // 0..63 tile row for A load
    const int ak = (tid & 3) * 8;      // 0,8,16,24 k-offset for A load
    const int bk = tid >> 3;           // 0..31 k row for B load
    const int bn = (tid & 7) * 16;     // 0..112 n-offset for B load

    for (int k0 = 0; k0 < IN_CH; k0 += BK) {
        // ---- stage A tile (64 x 32), transposed into sA[k][m] ----
        float4 va0 = make_float4(0.f, 0.f, 0.f, 0.f), va1 = va0;
        const int grow = row0 + ar;
        if (grow < M) {
            const float4* pa = (const float4*)(x + (size_t)grow * IN_CH + k0 + ak);
            va0 = pa[0]; va1 = pa[1];
        }
        sA[ak + 0][ar] = va0.x; sA[ak + 1][ar] = va0.y;
        sA[ak + 2][ar] = va0.z; sA[ak + 3][ar] = va0.w;
        sA[ak + 4][ar] = va1.x; sA[ak + 5][ar] = va1.y;
        sA[ak + 6][ar] = va1.z; sA[ak + 7][ar] = va1.w;

        // ---- stage B tile (32 x 128) ----
        {
            const float4* pb = (const float4*)(w + (size_t)(k0 + bk) * OUT_CH + bn);
            float4 vb0 = pb[0], vb1 = pb[1], vb2 = pb[2], vb3 = pb[3];
            float4* qb = (float4*)&sB[bk][bn];
            qb[0] = vb0; qb[1] = vb1; qb[2] = vb2; qb[3] = vb3;
        }
        __syncthreads();

#pragma unroll
        for (int k = 0; k < BK; ++k) {
            float4 a4 = *(const float4*)&sA[k][ty * 4];
            float4 b0 = *(const float4*)&sB[k][tx * 8];
            float4 b1 = *(const float4*)&sB[k][tx * 8 + 4];
            float a[4] = { a4.x, a4.y, a4.z, a4.w };
            float b[8] = { b0.x, b0.y, b0.z, b0.w, b1.x, b1.y, b1.z, b1.w };
#pragma unroll
            for (int i = 0; i < 4; ++i)
#pragma unroll
                for (int j = 0; j < 8; ++j)
                    acc[i][j] += a[i] * b[j];
        }
        __syncthreads();
    }

    // ---- epilogue: store xp, and per-row dots with att_src / att_dst ----
    float as[8], ad[8];
#pragma unroll
    for (int j = 0; j < 8; ++j) {
        as[j] = att_s[tx * 8 + j];
        ad[j] = att_d[tx * 8 + j];
    }
#pragma unroll
    for (int i = 0; i < 4; ++i) {
        const int r = row0 + ty * 4 + i;
        if (r < M) {   // uniform across the 16-lane tx group (same r)
            float4 o0 = make_float4(acc[i][0], acc[i][1], acc[i][2], acc[i][3]);
            float4 o1 = make_float4(acc[i][4], acc[i][5], acc[i][6], acc[i][7]);
            float4* q = (float4*)(xp + (size_t)r * OUT_CH + tx * 8);
            q[0] = o0; q[1] = o1;
            float ps = 0.f, pd = 0.f;
#pragma unroll
            for (int j = 0; j < 8; ++j) {
                ps += acc[i][j] * as[j];
                pd += acc[i][j] * ad[j];
            }
#pragma unroll
            for (int m = 8; m >= 1; m >>= 1) {
                ps += __shfl_xor(ps, m, 16);
                pd += __shfl_xor(pd, m, 16);
            }
            if (tx == 0) { asrc[r] = ps; adst[r] = pd; }
        }
    }
}

// ---------------- CSR build over dst (self-edges src==dst dropped) ----------------
__global__ void hist_kernel(const int* __restrict__ src, const int* __restrict__ dst,
                            int* __restrict__ deg, int E)
{
    int e = blockIdx.x * blockDim.x + threadIdx.x;
    if (e < E) {
        int s = src[e], d = dst[e];
        if (s != d) atomicAdd(&deg[d], 1);
    }
}

__global__ __launch_bounds__(1024) void scan_kernel(
    const int* __restrict__ deg, int* __restrict__ row_ptr,
    int* __restrict__ fill, int N)
{
    __shared__ int part[1024];
    const int t = threadIdx.x;
    const int chunk = (N + 1023) / 1024;
    const int b = t * chunk;
    const int e = min(N, b + chunk);
    int s = 0;
    for (int i = b; i < e; ++i) s += deg[i];
    part[t] = s;
    __syncthreads();
    // Hillis-Steele inclusive scan (read phase / write phase split by syncs)
    for (int off = 1; off < 1024; off <<= 1) {
        int v = (t >= off) ? part[t - off] : 0;
        __syncthreads();
        part[t] += v;
        __syncthreads();
    }
    int run = (t == 0) ? 0 : part[t - 1];
    for (int i = b; i < e; ++i) {
        row_ptr[i] = run;
        fill[i] = run;
        run += deg[i];
    }
    if (t == 1023) row_ptr[N] = part[1023];
}

__global__ void scatter_kernel(const int* __restrict__ src, const int* __restrict__ dst,
                               int* __restrict__ fill, int* __restrict__ col, int E)
{
    int e = blockIdx.x * blockDim.x + threadIdx.x;
    if (e < E) {
        int s = src[e], d = dst[e];
        if (s != d) {
            int pos = atomicAdd(&fill[d], 1);
            col[pos] = s;
        }
    }
}

// ---------------- Aggregation: one wave per dst node ----------------
// out[n] = ( ex_self*xp[n] + sum_e ex_e * xp[src_e] ) / (denom + EPS) + bias
// ex = exp(leaky_relu(asrc[s] + adst[n]))  -- unshifted softmax (shift-invariant;
// EPS contribution differs by < 1e-8 relative, far under threshold)
__global__ __launch_bounds__(256) void aggregate_kernel(
    const float* __restrict__ xp, const float* __restrict__ asrc,
    const float* __restrict__ adst, const int* __restrict__ row_ptr,
    const int* __restrict__ col, const float* __restrict__ bias,
    float* __restrict__ out, int N)
{
    const int wave = (blockIdx.x * blockDim.x + threadIdx.x) >> 6;
    const int lane = threadIdx.x & 63;
    if (wave >= N) return;
    const int n = wave;
    const float a_d = adst[n];

    float acc0 = 0.f, acc1 = 0.f, denom = 0.f;

    // self loop (always appended by reference)
    {
        float lg = asrc[n] + a_d;
        lg = (lg > 0.f) ? lg : lg * NEG_SLOPE;
        float ex = expf(lg);
        denom += ex;
        acc0 += ex * xp[(size_t)n * OUT_CH + lane];
        acc1 += ex * xp[(size_t)n * OUT_CH + 64 + lane];
    }

    const int beg = row_ptr[n];
    const int end = row_ptr[n + 1];
    for (int base = beg; base < end; base += 64) {
        const int idx = base + lane;
        int s = 0; float ex = 0.f;
        if (idx < end) {
            s = col[idx];
            float lg = asrc[s] + a_d;
            lg = (lg > 0.f) ? lg : lg * NEG_SLOPE;
            ex = expf(lg);
        }
        const int cnt = min(64, end - base);
        for (int j = 0; j < cnt; ++j) {
            const float exj = __shfl(ex, j, 64);
            const int   sj  = __shfl(s, j, 64);
            denom += exj;
            acc0 += exj * xp[(size_t)sj * OUT_CH + lane];
            acc1 += exj * xp[(size_t)sj * OUT_CH + 64 + lane];
        }
    }

    const float inv = 1.f / (denom + EPS);
    out[(size_t)n * OUT_CH + lane]      = acc0 * inv + bias[lane];
    out[(size_t)n * OUT_CH + 64 + lane] = acc1 * inv + bias[64 + lane];
}

// ---------------- launch ----------------
extern "C" void kernel_launch(void* const* d_in, const int* in_sizes, int n_in,
                              void* d_out, int out_size, void* d_ws, size_t ws_size,
                              hipStream_t stream)
{
    const float* x     = (const float*)d_in[0];
    const int*   ei    = (const int*)d_in[1];
    const float* w     = (const float*)d_in[2];
    const float* att_s = (const float*)d_in[3];
    const float* att_d = (const float*)d_in[4];
    const float* bias  = (const float*)d_in[5];
    float* out = (float*)d_out;

    const int N = in_sizes[0] / IN_CH;
    const int E = in_sizes[1] / 2;
    const int* src = ei;
    const int* dst = ei + E;

    char* p = (char*)d_ws;
    float* xp      = (float*)p; p += (size_t)N * OUT_CH * sizeof(float);
    float* asrc    = (float*)p; p += (size_t)N * sizeof(float);
    float* adst    = (float*)p; p += (size_t)N * sizeof(float);
    int*   deg     = (int*)p;   p += (size_t)N * sizeof(int);
    int*   row_ptr = (int*)p;   p += (size_t)(N + 1) * sizeof(int);
    int*   fill    = (int*)p;   p += (size_t)N * sizeof(int);
    int*   col     = (int*)p;   p += (size_t)E * sizeof(int);

    hipMemsetAsync(deg, 0, (size_t)N * sizeof(int), stream);

    gemm_alpha_kernel<<<(N + BM - 1) / BM, 256, 0, stream>>>(
        x, w, att_s, att_d, xp, asrc, adst, N);

    hist_kernel<<<(E + 255) / 256, 256, 0, stream>>>(src, dst, deg, E);
    scan_kernel<<<1, 1024, 0, stream>>>(deg, row_ptr, fill, N);
    scatter_kernel<<<(E + 255) / 256, 256, 0, stream>>>(src, dst, fill, col, E);

    aggregate_kernel<<<(N + 3) / 4, 256, 0, stream>>>(
        xp, asrc, adst, row_ptr, col, bias, out, N);
}

// Round 2
// 571.411 us; speedup vs baseline: 1.3695x; 1.3695x over previous
//
#include <hip/hip_runtime.h>
#include <cstdint>
#include <cstddef>

#define IN_CH 256
#define OUT_CH 128
#define NEG_SLOPE 0.2f
#define EPS 1e-16f

// ---------------- GEMM (xp = x @ W) + alpha epilogue ----------------
#define BM 64
#define BN 128
#define BK 32

__global__ __launch_bounds__(256) void gemm_alpha_kernel(
    const float* __restrict__ x, const float* __restrict__ w,
    const float* __restrict__ att_s, const float* __restrict__ att_d,
    float* __restrict__ xp, float* __restrict__ asrc, float* __restrict__ adst,
    int M)
{
    __shared__ float sA[BK][BM + 4];   // [k][m], +4 pad keeps float4 alignment
    __shared__ float sB[BK][BN];       // [k][n]
    const int tid = threadIdx.x;
    const int ty = tid >> 4;           // 0..15 : row group (4 rows each)
    const int tx = tid & 15;           // 0..15 : col group (8 cols each)
    const int row0 = blockIdx.x * BM;

    float acc[4][8];
#pragma unroll
    for (int i = 0; i < 4; ++i)
#pragma unroll
        for (int j = 0; j < 8; ++j) acc[i][j] = 0.f;

    const int ar = tid >> 2;           // 0..63 tile row for A load
    const int ak = (tid & 3) * 8;      // 0,8,16,24 k-offset for A load
    const int bk = tid >> 3;           // 0..31 k row for B load
    const int bn = (tid & 7) * 16;     // 0..112 n-offset for B load

    for (int k0 = 0; k0 < IN_CH; k0 += BK) {
        // ---- stage A tile (64 x 32), transposed into sA[k][m] ----
        float4 va0 = make_float4(0.f, 0.f, 0.f, 0.f), va1 = va0;
        const int grow = row0 + ar;
        if (grow < M) {
            const float4* pa = (const float4*)(x + (size_t)grow * IN_CH + k0 + ak);
            va0 = pa[0]; va1 = pa[1];
        }
        sA[ak + 0][ar] = va0.x; sA[ak + 1][ar] = va0.y;
        sA[ak + 2][ar] = va0.z; sA[ak + 3][ar] = va0.w;
        sA[ak + 4][ar] = va1.x; sA[ak + 5][ar] = va1.y;
        sA[ak + 6][ar] = va1.z; sA[ak + 7][ar] = va1.w;

        // ---- stage B tile (32 x 128) ----
        {
            const float4* pb = (const float4*)(w + (size_t)(k0 + bk) * OUT_CH + bn);
            float4 vb0 = pb[0], vb1 = pb[1], vb2 = pb[2], vb3 = pb[3];
            float4* qb = (float4*)&sB[bk][bn];
            qb[0] = vb0; qb[1] = vb1; qb[2] = vb2; qb[3] = vb3;
        }
        __syncthreads();

#pragma unroll
        for (int k = 0; k < BK; ++k) {
            float4 a4 = *(const float4*)&sA[k][ty * 4];
            float4 b0 = *(const float4*)&sB[k][tx * 8];
            float4 b1 = *(const float4*)&sB[k][tx * 8 + 4];
            float a[4] = { a4.x, a4.y, a4.z, a4.w };
            float b[8] = { b0.x, b0.y, b0.z, b0.w, b1.x, b1.y, b1.z, b1.w };
#pragma unroll
            for (int i = 0; i < 4; ++i)
#pragma unroll
                for (int j = 0; j < 8; ++j)
                    acc[i][j] += a[i] * b[j];
        }
        __syncthreads();
    }

    // ---- epilogue: store xp, and per-row dots with att_src / att_dst ----
    float as[8], ad[8];
#pragma unroll
    for (int j = 0; j < 8; ++j) {
        as[j] = att_s[tx * 8 + j];
        ad[j] = att_d[tx * 8 + j];
    }
#pragma unroll
    for (int i = 0; i < 4; ++i) {
        const int r = row0 + ty * 4 + i;
        if (r < M) {   // uniform across the 16-lane tx group (same r)
            float4 o0 = make_float4(acc[i][0], acc[i][1], acc[i][2], acc[i][3]);
            float4 o1 = make_float4(acc[i][4], acc[i][5], acc[i][6], acc[i][7]);
            float4* q = (float4*)(xp + (size_t)r * OUT_CH + tx * 8);
            q[0] = o0; q[1] = o1;
            float ps = 0.f, pd = 0.f;
#pragma unroll
            for (int j = 0; j < 8; ++j) {
                ps += acc[i][j] * as[j];
                pd += acc[i][j] * ad[j];
            }
#pragma unroll
            for (int m = 8; m >= 1; m >>= 1) {
                ps += __shfl_xor(ps, m, 16);
                pd += __shfl_xor(pd, m, 16);
            }
            if (tx == 0) { asrc[r] = ps; adst[r] = pd; }
        }
    }
}

// ---------------- CSR build over dst (self-edges src==dst dropped) ----------------
__global__ void hist_kernel(const int* __restrict__ src, const int* __restrict__ dst,
                            int* __restrict__ deg, int E)
{
    int e = blockIdx.x * blockDim.x + threadIdx.x;
    if (e < E) {
        int s = src[e], d = dst[e];
        if (s != d) atomicAdd(&deg[d], 1);
    }
}

// ---- two-level scan: 256 blocks x 256 threads ----
#define SCAN_NB 256
#define SCAN_NT 256

__global__ __launch_bounds__(SCAN_NT) void scan_partial_kernel(
    const int* __restrict__ deg, int* __restrict__ bsum, int N)
{
    __shared__ int sh[SCAN_NT];
    const int chunk = (N + SCAN_NB - 1) / SCAN_NB;        // per block
    const int sub   = (chunk + SCAN_NT - 1) / SCAN_NT;    // per thread
    const int b0 = blockIdx.x * chunk;
    const int t0 = b0 + threadIdx.x * sub;
    const int t1 = min(min(b0 + chunk, t0 + sub), N);
    int s = 0;
    for (int i = t0; i < t1; ++i) s += deg[i];
    sh[threadIdx.x] = s;
    __syncthreads();
    for (int off = SCAN_NT / 2; off > 0; off >>= 1) {
        if (threadIdx.x < off) sh[threadIdx.x] += sh[threadIdx.x + off];
        __syncthreads();
    }
    if (threadIdx.x == 0) bsum[blockIdx.x] = sh[0];
}

__global__ __launch_bounds__(SCAN_NB) void scan_blocksums_kernel(
    const int* __restrict__ bsum, int* __restrict__ boff,
    int* __restrict__ row_ptr, int N)
{
    __shared__ int sh[SCAN_NB];
    const int t = threadIdx.x;
    sh[t] = bsum[t];
    __syncthreads();
    for (int off = 1; off < SCAN_NB; off <<= 1) {
        int v = (t >= off) ? sh[t - off] : 0;
        __syncthreads();
        sh[t] += v;
        __syncthreads();
    }
    boff[t] = (t == 0) ? 0 : sh[t - 1];   // exclusive
    if (t == SCAN_NB - 1) row_ptr[N] = sh[t];
}

__global__ __launch_bounds__(SCAN_NT) void scan_fill_kernel(
    const int* __restrict__ deg, const int* __restrict__ boff,
    int* __restrict__ row_ptr, int* __restrict__ fill, int N)
{
    __shared__ int sh[SCAN_NT];
    const int chunk = (N + SCAN_NB - 1) / SCAN_NB;
    const int sub   = (chunk + SCAN_NT - 1) / SCAN_NT;
    const int b0 = blockIdx.x * chunk;
    const int t0 = b0 + threadIdx.x * sub;
    const int t1 = min(min(b0 + chunk, t0 + sub), N);
    int s = 0;
    for (int i = t0; i < t1; ++i) s += deg[i];
    sh[threadIdx.x] = s;
    __syncthreads();
    for (int off = 1; off < SCAN_NT; off <<= 1) {
        int v = (threadIdx.x >= off) ? sh[threadIdx.x - off] : 0;
        __syncthreads();
        sh[threadIdx.x] += v;
        __syncthreads();
    }
    int run = boff[blockIdx.x] + ((threadIdx.x == 0) ? 0 : sh[threadIdx.x - 1]);
    for (int i = t0; i < t1; ++i) {
        row_ptr[i] = run;
        fill[i] = run;
        run += deg[i];
    }
}

__global__ void scatter_kernel(const int* __restrict__ src, const int* __restrict__ dst,
                               int* __restrict__ fill, int* __restrict__ col, int E)
{
    int e = blockIdx.x * blockDim.x + threadIdx.x;
    if (e < E) {
        int s = src[e], d = dst[e];
        if (s != d) {
            int pos = atomicAdd(&fill[d], 1);
            col[pos] = s;
        }
    }
}

// ---------------- Aggregation: one wave per dst node ----------------
// out[n] = ( ex_self*xp[n] + sum_e ex_e * xp[src_e] ) / (denom + EPS) + bias
// ex = exp(leaky_relu(asrc[s] + adst[n]))  -- unshifted softmax (shift-invariant;
// EPS contribution differs by < 1e-8 relative, far under threshold)
__global__ __launch_bounds__(256) void aggregate_kernel(
    const float* __restrict__ xp, const float* __restrict__ asrc,
    const float* __restrict__ adst, const int* __restrict__ row_ptr,
    const int* __restrict__ col, const float* __restrict__ bias,
    float* __restrict__ out, int N)
{
    const int wave = (blockIdx.x * blockDim.x + threadIdx.x) >> 6;
    const int lane = threadIdx.x & 63;
    if (wave >= N) return;
    const int n = wave;
    const float a_d = adst[n];

    const float2* xp2 = (const float2*)xp;   // 64 float2 per row
    float accx = 0.f, accy = 0.f, denom = 0.f;

    // self loop (always appended by reference)
    {
        float lg = asrc[n] + a_d;
        lg = (lg > 0.f) ? lg : lg * NEG_SLOPE;
        float ex = __expf(lg);
        denom += ex;
        float2 v = xp2[(size_t)n * 64 + lane];
        accx += ex * v.x; accy += ex * v.y;
    }

    const int beg = row_ptr[n];
    const int end = row_ptr[n + 1];
    for (int base = beg; base < end; base += 64) {
        const int idx = base + lane;
        int s = 0; float ex = 0.f;
        if (idx < end) {
            s = col[idx];
            float lg = asrc[s] + a_d;
            lg = (lg > 0.f) ? lg : lg * NEG_SLOPE;
            ex = __expf(lg);
        }
        const int cnt = min(64, end - base);
        for (int j = 0; j < cnt; ++j) {
            const float exj = __shfl(ex, j, 64);
            const int   sj  = __shfl(s, j, 64);
            denom += exj;
            float2 v = xp2[(size_t)sj * 64 + lane];
            accx += exj * v.x; accy += exj * v.y;
        }
    }

    const float inv = 1.f / (denom + EPS);
    const float2* bias2 = (const float2*)bias;
    float2 bv = bias2[lane];
    float2 o; o.x = accx * inv + bv.x; o.y = accy * inv + bv.y;
    ((float2*)out)[(size_t)n * 64 + lane] = o;
}

// ---------------- launch ----------------
extern "C" void kernel_launch(void* const* d_in, const int* in_sizes, int n_in,
                              void* d_out, int out_size, void* d_ws, size_t ws_size,
                              hipStream_t stream)
{
    const float* x     = (const float*)d_in[0];
    const int*   ei    = (const int*)d_in[1];
    const float* w     = (const float*)d_in[2];
    const float* att_s = (const float*)d_in[3];
    const float* att_d = (const float*)d_in[4];
    const float* bias  = (const float*)d_in[5];
    float* out = (float*)d_out;

    const int N = in_sizes[0] / IN_CH;
    const int E = in_sizes[1] / 2;
    const int* src = ei;
    const int* dst = ei + E;

    char* p = (char*)d_ws;
    float* xp      = (float*)p; p += (size_t)N * OUT_CH * sizeof(float);
    float* asrc    = (float*)p; p += (size_t)N * sizeof(float);
    float* adst    = (float*)p; p += (size_t)N * sizeof(float);
    int*   deg     = (int*)p;   p += (size_t)N * sizeof(int);
    int*   row_ptr = (int*)p;   p += (size_t)(N + 1) * sizeof(int);
    int*   fill    = (int*)p;   p += (size_t)N * sizeof(int);
    int*   bsum    = (int*)p;   p += (size_t)SCAN_NB * sizeof(int);
    int*   boff    = (int*)p;   p += (size_t)SCAN_NB * sizeof(int);
    int*   col     = (int*)p;   p += (size_t)E * sizeof(int);

    hipMemsetAsync(deg, 0, (size_t)N * sizeof(int), stream);

    gemm_alpha_kernel<<<(N + BM - 1) / BM, 256, 0, stream>>>(
        x, w, att_s, att_d, xp, asrc, adst, N);

    hist_kernel<<<(E + 255) / 256, 256, 0, stream>>>(src, dst, deg, E);
    scan_partial_kernel<<<SCAN_NB, SCAN_NT, 0, stream>>>(deg, bsum, N);
    scan_blocksums_kernel<<<1, SCAN_NB, 0, stream>>>(bsum, boff, row_ptr, N);
    scan_fill_kernel<<<SCAN_NB, SCAN_NT, 0, stream>>>(deg, boff, row_ptr, fill, N);
    scatter_kernel<<<(E + 255) / 256, 256, 0, stream>>>(src, dst, fill, col, E);

    aggregate_kernel<<<(N + 3) / 4, 256, 0, stream>>>(
        xp, asrc, adst, row_ptr, col, bias, out, N);
}

// Round 3
// 436.912 us; speedup vs baseline: 1.7910x; 1.3078x over previous
//
#include <hip/hip_runtime.h>
#include <cstdint>
#include <cstddef>

#define IN_CH 256
#define OUT_CH 128
#define NEG_SLOPE 0.2f
#define EPS 1e-16f

// ---------------- GEMM (xp = x @ W) + alpha epilogue ----------------
#define BM 64
#define BN 128
#define BK 32

__device__ __forceinline__ void gemm_body(
    int bid,
    const float* __restrict__ x, const float* __restrict__ w,
    const float* __restrict__ att_s, const float* __restrict__ att_d,
    float* __restrict__ xp, float* __restrict__ asrc, float* __restrict__ adst,
    int M)
{
    __shared__ float sA[BK][BM + 4];
    __shared__ float sB[BK][BN];
    const int tid = threadIdx.x;
    const int ty = tid >> 4;
    const int tx = tid & 15;
    const int row0 = bid * BM;

    float acc[4][8];
#pragma unroll
    for (int i = 0; i < 4; ++i)
#pragma unroll
        for (int j = 0; j < 8; ++j) acc[i][j] = 0.f;

    const int ar = tid >> 2;
    const int ak = (tid & 3) * 8;
    const int bk = tid >> 3;
    const int bn = (tid & 7) * 16;

    for (int k0 = 0; k0 < IN_CH; k0 += BK) {
        float4 va0 = make_float4(0.f, 0.f, 0.f, 0.f), va1 = va0;
        const int grow = row0 + ar;
        if (grow < M) {
            const float4* pa = (const float4*)(x + (size_t)grow * IN_CH + k0 + ak);
            va0 = pa[0]; va1 = pa[1];
        }
        sA[ak + 0][ar] = va0.x; sA[ak + 1][ar] = va0.y;
        sA[ak + 2][ar] = va0.z; sA[ak + 3][ar] = va0.w;
        sA[ak + 4][ar] = va1.x; sA[ak + 5][ar] = va1.y;
        sA[ak + 6][ar] = va1.z; sA[ak + 7][ar] = va1.w;

        {
            const float4* pb = (const float4*)(w + (size_t)(k0 + bk) * OUT_CH + bn);
            float4 vb0 = pb[0], vb1 = pb[1], vb2 = pb[2], vb3 = pb[3];
            float4* qb = (float4*)&sB[bk][bn];
            qb[0] = vb0; qb[1] = vb1; qb[2] = vb2; qb[3] = vb3;
        }
        __syncthreads();

#pragma unroll
        for (int k = 0; k < BK; ++k) {
            float4 a4 = *(const float4*)&sA[k][ty * 4];
            float4 b0 = *(const float4*)&sB[k][tx * 8];
            float4 b1 = *(const float4*)&sB[k][tx * 8 + 4];
            float a[4] = { a4.x, a4.y, a4.z, a4.w };
            float b[8] = { b0.x, b0.y, b0.z, b0.w, b1.x, b1.y, b1.z, b1.w };
#pragma unroll
            for (int i = 0; i < 4; ++i)
#pragma unroll
                for (int j = 0; j < 8; ++j)
                    acc[i][j] += a[i] * b[j];
        }
        __syncthreads();
    }

    float as[8], ad[8];
#pragma unroll
    for (int j = 0; j < 8; ++j) {
        as[j] = att_s[tx * 8 + j];
        ad[j] = att_d[tx * 8 + j];
    }
#pragma unroll
    for (int i = 0; i < 4; ++i) {
        const int r = row0 + ty * 4 + i;
        if (r < M) {
            float4 o0 = make_float4(acc[i][0], acc[i][1], acc[i][2], acc[i][3]);
            float4 o1 = make_float4(acc[i][4], acc[i][5], acc[i][6], acc[i][7]);
            float4* q = (float4*)(xp + (size_t)r * OUT_CH + tx * 8);
            q[0] = o0; q[1] = o1;
            float ps = 0.f, pd = 0.f;
#pragma unroll
            for (int j = 0; j < 8; ++j) {
                ps += acc[i][j] * as[j];
                pd += acc[i][j] * ad[j];
            }
#pragma unroll
            for (int m = 8; m >= 1; m >>= 1) {
                ps += __shfl_xor(ps, m, 16);
                pd += __shfl_xor(pd, m, 16);
            }
            if (tx == 0) { asrc[r] = ps; adst[r] = pd; }
        }
    }
}

// hist + position-within-row, 4 edges/thread (independent atomic chains).
// pw[e] = old count of dst[e]; the atomic's return value does double duty so
// the later scatter needs NO atomic at all.
__device__ __forceinline__ void hist_body(
    int bid, int nblk,
    const int* __restrict__ src, const int* __restrict__ dst,
    int* __restrict__ deg, int* __restrict__ pw, int E)
{
    const int T = nblk * 256;            // stride
    const int e0 = bid * 256 + threadIdx.x;
#pragma unroll
    for (int k = 0; k < 4; ++k) {
        const int e = e0 + k * T;
        if (e < E) {
            int s = src[e], d = dst[e];
            if (s != d) pw[e] = atomicAdd(&deg[d], 1);
        }
    }
}

__global__ __launch_bounds__(256) void fused_gemm_hist_kernel(
    const float* __restrict__ x, const float* __restrict__ w,
    const float* __restrict__ att_s, const float* __restrict__ att_d,
    float* __restrict__ xp, float* __restrict__ asrc, float* __restrict__ adst,
    int M,
    const int* __restrict__ src, const int* __restrict__ dst,
    int* __restrict__ deg, int* __restrict__ pw, int E,
    int gemm_blocks, int hist_blocks)
{
    if ((int)blockIdx.x < gemm_blocks) {
        gemm_body(blockIdx.x, x, w, att_s, att_d, xp, asrc, adst, M);
    } else {
        hist_body(blockIdx.x - gemm_blocks, hist_blocks, src, dst, deg, pw, E);
    }
}

// ---- two-level scan: 256 blocks x 256 threads ----
#define SCAN_NB 256
#define SCAN_NT 256

__global__ __launch_bounds__(SCAN_NT) void scan_partial_kernel(
    const int* __restrict__ deg, int* __restrict__ bsum, int N)
{
    __shared__ int sh[SCAN_NT];
    const int chunk = (N + SCAN_NB - 1) / SCAN_NB;
    const int sub   = (chunk + SCAN_NT - 1) / SCAN_NT;
    const int b0 = blockIdx.x * chunk;
    const int t0 = b0 + threadIdx.x * sub;
    const int t1 = min(min(b0 + chunk, t0 + sub), N);
    int s = 0;
    for (int i = t0; i < t1; ++i) s += deg[i];
    sh[threadIdx.x] = s;
    __syncthreads();
    for (int off = SCAN_NT / 2; off > 0; off >>= 1) {
        if (threadIdx.x < off) sh[threadIdx.x] += sh[threadIdx.x + off];
        __syncthreads();
    }
    if (threadIdx.x == 0) bsum[blockIdx.x] = sh[0];
}

__global__ __launch_bounds__(SCAN_NB) void scan_blocksums_kernel(
    const int* __restrict__ bsum, int* __restrict__ boff,
    int* __restrict__ row_ptr, int N)
{
    __shared__ int sh[SCAN_NB];
    const int t = threadIdx.x;
    sh[t] = bsum[t];
    __syncthreads();
    for (int off = 1; off < SCAN_NB; off <<= 1) {
        int v = (t >= off) ? sh[t - off] : 0;
        __syncthreads();
        sh[t] += v;
        __syncthreads();
    }
    boff[t] = (t == 0) ? 0 : sh[t - 1];
    if (t == SCAN_NB - 1) row_ptr[N] = sh[t];
}

__global__ __launch_bounds__(SCAN_NT) void scan_fill_kernel(
    const int* __restrict__ deg, const int* __restrict__ boff,
    int* __restrict__ row_ptr, int N)
{
    __shared__ int sh[SCAN_NT];
    const int chunk = (N + SCAN_NB - 1) / SCAN_NB;
    const int sub   = (chunk + SCAN_NT - 1) / SCAN_NT;
    const int b0 = blockIdx.x * chunk;
    const int t0 = b0 + threadIdx.x * sub;
    const int t1 = min(min(b0 + chunk, t0 + sub), N);
    int s = 0;
    for (int i = t0; i < t1; ++i) s += deg[i];
    sh[threadIdx.x] = s;
    __syncthreads();
    for (int off = 1; off < SCAN_NT; off <<= 1) {
        int v = (threadIdx.x >= off) ? sh[threadIdx.x - off] : 0;
        __syncthreads();
        sh[threadIdx.x] += v;
        __syncthreads();
    }
    int run = boff[blockIdx.x] + ((threadIdx.x == 0) ? 0 : sh[threadIdx.x - 1]);
    for (int i = t0; i < t1; ++i) {
        row_ptr[i] = run;
        run += deg[i];
    }
}

// atomic-free scatter: position was precomputed in hist. 4 edges/thread,
// all stores independent -> bounded only by random-write BW.
__global__ __launch_bounds__(256) void scatter_kernel(
    const int* __restrict__ src, const int* __restrict__ dst,
    const int* __restrict__ row_ptr, const int* __restrict__ pw,
    int* __restrict__ col, int E, int nblk)
{
    const int T = nblk * 256;
    const int e0 = blockIdx.x * 256 + threadIdx.x;
#pragma unroll
    for (int k = 0; k < 4; ++k) {
        const int e = e0 + k * T;
        if (e < E) {
            int s = src[e], d = dst[e];
            if (s != d) col[row_ptr[d] + pw[e]] = s;
        }
    }
}

// ---------------- Aggregation: one wave per dst node ----------------
// out[n] = ( ex_self*xp[n] + sum_e ex_e * xp[src_e] ) / (denom + EPS) + bias
// unshifted softmax (shift-invariant; EPS effect < 1e-8 relative)
__global__ __launch_bounds__(256) void aggregate_kernel(
    const float* __restrict__ xp, const float* __restrict__ asrc,
    const float* __restrict__ adst, const int* __restrict__ row_ptr,
    const int* __restrict__ col, const float* __restrict__ bias,
    float* __restrict__ out, int N)
{
    const int wave = (blockIdx.x * blockDim.x + threadIdx.x) >> 6;
    const int lane = threadIdx.x & 63;
    if (wave >= N) return;
    const int n = wave;
    const float a_d = adst[n];

    const float2* xp2 = (const float2*)xp;
    float accx = 0.f, accy = 0.f, denom = 0.f;

    {
        float lg = asrc[n] + a_d;
        lg = (lg > 0.f) ? lg : lg * NEG_SLOPE;
        float ex = __expf(lg);
        denom += ex;
        float2 v = xp2[(size_t)n * 64 + lane];
        accx += ex * v.x; accy += ex * v.y;
    }

    const int beg = row_ptr[n];
    const int end = row_ptr[n + 1];
    for (int base = beg; base < end; base += 64) {
        const int idx = base + lane;
        int s = 0; float ex = 0.f;
        if (idx < end) {
            s = col[idx];
            float lg = asrc[s] + a_d;
            lg = (lg > 0.f) ? lg : lg * NEG_SLOPE;
            ex = __expf(lg);
        }
        const int cnt = min(64, end - base);
        for (int j = 0; j < cnt; ++j) {
            const float exj = __shfl(ex, j, 64);
            const int   sj  = __shfl(s, j, 64);
            denom += exj;
            float2 v = xp2[(size_t)sj * 64 + lane];
            accx += exj * v.x; accy += exj * v.y;
        }
    }

    const float inv = 1.f / (denom + EPS);
    const float2* bias2 = (const float2*)bias;
    float2 bv = bias2[lane];
    float2 o; o.x = accx * inv + bv.x; o.y = accy * inv + bv.y;
    ((float2*)out)[(size_t)n * 64 + lane] = o;
}

// ---------------- launch ----------------
extern "C" void kernel_launch(void* const* d_in, const int* in_sizes, int n_in,
                              void* d_out, int out_size, void* d_ws, size_t ws_size,
                              hipStream_t stream)
{
    const float* x     = (const float*)d_in[0];
    const int*   ei    = (const int*)d_in[1];
    const float* w     = (const float*)d_in[2];
    const float* att_s = (const float*)d_in[3];
    const float* att_d = (const float*)d_in[4];
    const float* bias  = (const float*)d_in[5];
    float* out = (float*)d_out;

    const int N = in_sizes[0] / IN_CH;
    const int E = in_sizes[1] / 2;
    const int* src = ei;
    const int* dst = ei + E;

    char* p = (char*)d_ws;
    float* xp      = (float*)p; p += (size_t)N * OUT_CH * sizeof(float);
    float* asrc    = (float*)p; p += (size_t)N * sizeof(float);
    float* adst    = (float*)p; p += (size_t)N * sizeof(float);
    int*   deg     = (int*)p;   p += (size_t)N * sizeof(int);
    int*   row_ptr = (int*)p;   p += (size_t)(N + 1) * sizeof(int);
    int*   bsum    = (int*)p;   p += (size_t)SCAN_NB * sizeof(int);
    int*   boff    = (int*)p;   p += (size_t)SCAN_NB * sizeof(int);
    int*   pw      = (int*)p;   p += (size_t)E * sizeof(int);
    int*   col     = (int*)p;   p += (size_t)E * sizeof(int);

    hipMemsetAsync(deg, 0, (size_t)N * sizeof(int), stream);

    const int gemm_blocks = (N + BM - 1) / BM;
    const int hist_blocks = (E + 256 * 4 - 1) / (256 * 4);
    fused_gemm_hist_kernel<<<gemm_blocks + hist_blocks, 256, 0, stream>>>(
        x, w, att_s, att_d, xp, asrc, adst, N,
        src, dst, deg, pw, E, gemm_blocks, hist_blocks);

    scan_partial_kernel<<<SCAN_NB, SCAN_NT, 0, stream>>>(deg, bsum, N);
    scan_blocksums_kernel<<<1, SCAN_NB, 0, stream>>>(bsum, boff, row_ptr, N);
    scan_fill_kernel<<<SCAN_NB, SCAN_NT, 0, stream>>>(deg, boff, row_ptr, N);

    const int sc_blocks = (E + 256 * 4 - 1) / (256 * 4);
    scatter_kernel<<<sc_blocks, 256, 0, stream>>>(src, dst, row_ptr, pw, col, E, sc_blocks);

    aggregate_kernel<<<(N + 3) / 4, 256, 0, stream>>>(
        xp, asrc, adst, row_ptr, col, bias, out, N);
}

// Round 4
// 381.221 us; speedup vs baseline: 2.0527x; 1.1461x over previous
//
#include <hip/hip_runtime.h>
#include <cstdint>
#include <cstddef>

#define IN_CH 256
#define OUT_CH 128
#define NEG_SLOPE 0.2f
#define EPS 1e-16f

typedef __attribute__((ext_vector_type(8))) short bf16x8;
typedef __attribute__((ext_vector_type(4))) float f32x4;

__device__ __forceinline__ unsigned short f2bf(float f) {
    unsigned int u = __float_as_uint(f);
    return (unsigned short)((u + 0x7fffu + ((u >> 16) & 1u)) >> 16);
}

// ---------------- one-time: w [256][128] f32 -> wt [128][256] bf16 (transposed) ----------------
__global__ __launch_bounds__(256) void convert_w_kernel(const float* __restrict__ w,
                                                        unsigned short* __restrict__ wt)
{
    const int n = blockIdx.x;     // 0..127  (output row = column of w)
    const int k = threadIdx.x;    // 0..255
    wt[(size_t)n * IN_CH + k] = f2bf(w[(size_t)k * OUT_CH + n]);
}

// ---------------- MFMA GEMM body: 64 rows x 128 cols per block, no LDS ----------------
// wave w computes rows [bid*64 + w*16, +16), all 128 cols as 8 16x16 tiles.
// A-frag: A[m=lane&15][k=quad*8+j]  loaded direct from x (f32->bf16 in-reg)
// B-frag: B[k=quad*8+j][n=lane&15]  loaded direct from wt[n][k] (bf16, L2-hot)
// C/D:    D[row=quad*4+r][col=lane&15]   (verified layout, m89/m91)
__device__ __forceinline__ void gemm_body(
    int bid, const float* __restrict__ x, const unsigned short* __restrict__ wt,
    const float* __restrict__ att_s, const float* __restrict__ att_d,
    unsigned short* __restrict__ xpb, float* __restrict__ asrc, float* __restrict__ adst,
    int M)
{
    const int tid  = threadIdx.x;
    const int wv   = tid >> 6;
    const int lane = tid & 63;
    const int lm   = lane & 15;
    const int quad = lane >> 4;
    const int arow = bid * 64 + wv * 16 + lm;
    const bool av  = arow < M;
    const float* xrow = x + (size_t)arow * IN_CH + quad * 8;

    f32x4 acc[8];
#pragma unroll
    for (int t = 0; t < 8; ++t) acc[t] = (f32x4){0.f, 0.f, 0.f, 0.f};

#pragma unroll
    for (int kk = 0; kk < 8; ++kk) {
        const int k0 = kk * 32;
        bf16x8 af = {0, 0, 0, 0, 0, 0, 0, 0};
        if (av) {
            float4 a0 = *(const float4*)(xrow + k0);
            float4 a1 = *(const float4*)(xrow + k0 + 4);
            af[0] = (short)f2bf(a0.x); af[1] = (short)f2bf(a0.y);
            af[2] = (short)f2bf(a0.z); af[3] = (short)f2bf(a0.w);
            af[4] = (short)f2bf(a1.x); af[5] = (short)f2bf(a1.y);
            af[6] = (short)f2bf(a1.z); af[7] = (short)f2bf(a1.w);
        }
#pragma unroll
        for (int t = 0; t < 8; ++t) {
            bf16x8 bf = *(const bf16x8*)(wt + (size_t)(16 * t + lm) * IN_CH + k0 + quad * 8);
            acc[t] = __builtin_amdgcn_mfma_f32_16x16x32_bf16(af, bf, acc[t], 0, 0, 0);
        }
    }

    // epilogue: write bf16 xp + per-row att dots (reduced over the 16 lm lanes)
    float asw[8], adw[8];
#pragma unroll
    for (int t = 0; t < 8; ++t) {
        asw[t] = att_s[16 * t + lm];
        adw[t] = att_d[16 * t + lm];
    }
#pragma unroll
    for (int r = 0; r < 4; ++r) {
        const int orow = bid * 64 + wv * 16 + quad * 4 + r;
        if (orow < M) {   // uniform across lm group
            float ps = 0.f, pd = 0.f;
            unsigned short* xr = xpb + (size_t)orow * OUT_CH + lm;
#pragma unroll
            for (int t = 0; t < 8; ++t) {
                float v = acc[t][r];
                xr[16 * t] = f2bf(v);
                ps += v * asw[t];
                pd += v * adw[t];
            }
#pragma unroll
            for (int m = 1; m < 16; m <<= 1) {
                ps += __shfl_xor(ps, m, 16);
                pd += __shfl_xor(pd, m, 16);
            }
            if (lm == 0) { asrc[orow] = ps; adst[orow] = pd; }
        }
    }
}

// hist + position-within-row, 8 edges/thread (independent atomic chains)
__device__ __forceinline__ void hist_body(
    int bid, int nblk,
    const int* __restrict__ src, const int* __restrict__ dst,
    int* __restrict__ deg, int* __restrict__ pw, int E)
{
    const int T = nblk * 256;
    const int e0 = bid * 256 + threadIdx.x;
#pragma unroll
    for (int k = 0; k < 8; ++k) {
        const int e = e0 + k * T;
        if (e < E) {
            int s = src[e], d = dst[e];
            if (s != d) pw[e] = atomicAdd(&deg[d], 1);
        }
    }
}

__global__ __launch_bounds__(256) void fused_gemm_hist_kernel(
    const float* __restrict__ x, const unsigned short* __restrict__ wt,
    const float* __restrict__ att_s, const float* __restrict__ att_d,
    unsigned short* __restrict__ xpb, float* __restrict__ asrc, float* __restrict__ adst,
    int M,
    const int* __restrict__ src, const int* __restrict__ dst,
    int* __restrict__ deg, int* __restrict__ pw, int E,
    int hist_blocks)
{
    // hist blocks first: latency-bound atomics co-resident under the GEMM
    if ((int)blockIdx.x < hist_blocks)
        hist_body(blockIdx.x, hist_blocks, src, dst, deg, pw, E);
    else
        gemm_body(blockIdx.x - hist_blocks, x, wt, att_s, att_d, xpb, asrc, adst, M);
}

// ---- two-level scan: 256 blocks x 256 threads ----
#define SCAN_NB 256
#define SCAN_NT 256

__global__ __launch_bounds__(SCAN_NT) void scan_partial_kernel(
    const int* __restrict__ deg, int* __restrict__ bsum, int N)
{
    __shared__ int sh[SCAN_NT];
    const int chunk = (N + SCAN_NB - 1) / SCAN_NB;
    const int sub   = (chunk + SCAN_NT - 1) / SCAN_NT;
    const int b0 = blockIdx.x * chunk;
    const int t0 = b0 + threadIdx.x * sub;
    const int t1 = min(min(b0 + chunk, t0 + sub), N);
    int s = 0;
    for (int i = t0; i < t1; ++i) s += deg[i];
    sh[threadIdx.x] = s;
    __syncthreads();
    for (int off = SCAN_NT / 2; off > 0; off >>= 1) {
        if (threadIdx.x < off) sh[threadIdx.x] += sh[threadIdx.x + off];
        __syncthreads();
    }
    if (threadIdx.x == 0) bsum[blockIdx.x] = sh[0];
}

__global__ __launch_bounds__(SCAN_NB) void scan_blocksums_kernel(
    const int* __restrict__ bsum, int* __restrict__ boff,
    int* __restrict__ row_ptr, int N)
{
    __shared__ int sh[SCAN_NB];
    const int t = threadIdx.x;
    sh[t] = bsum[t];
    __syncthreads();
    for (int off = 1; off < SCAN_NB; off <<= 1) {
        int v = (t >= off) ? sh[t - off] : 0;
        __syncthreads();
        sh[t] += v;
        __syncthreads();
    }
    boff[t] = (t == 0) ? 0 : sh[t - 1];
    if (t == SCAN_NB - 1) row_ptr[N] = sh[t];
}

__global__ __launch_bounds__(SCAN_NT) void scan_fill_kernel(
    const int* __restrict__ deg, const int* __restrict__ boff,
    int* __restrict__ row_ptr, int N)
{
    __shared__ int sh[SCAN_NT];
    const int chunk = (N + SCAN_NB - 1) / SCAN_NB;
    const int sub   = (chunk + SCAN_NT - 1) / SCAN_NT;
    const int b0 = blockIdx.x * chunk;
    const int t0 = b0 + threadIdx.x * sub;
    const int t1 = min(min(b0 + chunk, t0 + sub), N);
    int s = 0;
    for (int i = t0; i < t1; ++i) s += deg[i];
    sh[threadIdx.x] = s;
    __syncthreads();
    for (int off = 1; off < SCAN_NT; off <<= 1) {
        int v = (threadIdx.x >= off) ? sh[threadIdx.x - off] : 0;
        __syncthreads();
        sh[threadIdx.x] += v;
        __syncthreads();
    }
    int run = boff[blockIdx.x] + ((threadIdx.x == 0) ? 0 : sh[threadIdx.x - 1]);
    for (int i = t0; i < t1; ++i) {
        row_ptr[i] = run;
        run += deg[i];
    }
}

// atomic-free scatter, 8 edges/thread
__global__ __launch_bounds__(256) void scatter_kernel(
    const int* __restrict__ src, const int* __restrict__ dst,
    const int* __restrict__ row_ptr, const int* __restrict__ pw,
    int* __restrict__ col, int E, int nblk)
{
    const int T = nblk * 256;
    const int e0 = blockIdx.x * 256 + threadIdx.x;
#pragma unroll
    for (int k = 0; k < 8; ++k) {
        const int e = e0 + k * T;
        if (e < E) {
            int s = src[e], d = dst[e];
            if (s != d) col[row_ptr[d] + pw[e]] = s;
        }
    }
}

// ---------------- Aggregation: one wave per dst node, bf16 xp gathers ----------------
__global__ __launch_bounds__(256) void aggregate_kernel(
    const unsigned short* __restrict__ xpb, const float* __restrict__ asrc,
    const float* __restrict__ adst, const int* __restrict__ row_ptr,
    const int* __restrict__ col, const float* __restrict__ bias,
    float* __restrict__ out, int N)
{
    const int n = (int)((blockIdx.x * blockDim.x + threadIdx.x) >> 6);
    const int lane = threadIdx.x & 63;
    if (n >= N) return;
    const float a_d = adst[n];
    const unsigned int* xpw = (const unsigned int*)xpb;   // 64 uints (=2 bf16) per row

    float ax0 = 0.f, ay0 = 0.f, ax1 = 0.f, ay1 = 0.f;
    float ax2 = 0.f, ay2 = 0.f, ax3 = 0.f, ay3 = 0.f;
    float den = 0.f;

    { // self loop
        float lg = asrc[n] + a_d;
        lg = (lg > 0.f) ? lg : lg * NEG_SLOPE;
        float ex = __expf(lg);
        den += ex;
        unsigned int v = xpw[(size_t)n * 64 + lane];
        ax0 += ex * __uint_as_float(v << 16);
        ay0 += ex * __uint_as_float(v & 0xffff0000u);
    }

    const int beg = row_ptr[n], end = row_ptr[n + 1];
    for (int base = beg; base < end; base += 64) {
        const int idx = base + lane;
        int s = 0; float ex = 0.f;
        if (idx < end) {
            s = col[idx];
            float lg = asrc[s] + a_d;
            lg = (lg > 0.f) ? lg : lg * NEG_SLOPE;
            ex = __expf(lg);
        }
        const int cnt = min(64, end - base);
        int j = 0;
        for (; j + 4 <= cnt; j += 4) {
            float e0 = __shfl(ex, j, 64),     e1 = __shfl(ex, j + 1, 64);
            float e2 = __shfl(ex, j + 2, 64), e3 = __shfl(ex, j + 3, 64);
            int   s0 = __shfl(s, j, 64),      s1 = __shfl(s, j + 1, 64);
            int   s2 = __shfl(s, j + 2, 64),  s3 = __shfl(s, j + 3, 64);
            unsigned int v0 = xpw[(size_t)s0 * 64 + lane];
            unsigned int v1 = xpw[(size_t)s1 * 64 + lane];
            unsigned int v2 = xpw[(size_t)s2 * 64 + lane];
            unsigned int v3 = xpw[(size_t)s3 * 64 + lane];
            den += (e0 + e1) + (e2 + e3);
            ax0 += e0 * __uint_as_float(v0 << 16);
            ay0 += e0 * __uint_as_float(v0 & 0xffff0000u);
            ax1 += e1 * __uint_as_float(v1 << 16);
            ay1 += e1 * __uint_as_float(v1 & 0xffff0000u);
            ax2 += e2 * __uint_as_float(v2 << 16);
            ay2 += e2 * __uint_as_float(v2 & 0xffff0000u);
            ax3 += e3 * __uint_as_float(v3 << 16);
            ay3 += e3 * __uint_as_float(v3 & 0xffff0000u);
        }
        for (; j < cnt; ++j) {
            float e0 = __shfl(ex, j, 64);
            int   s0 = __shfl(s, j, 64);
            unsigned int v0 = xpw[(size_t)s0 * 64 + lane];
            den += e0;
            ax0 += e0 * __uint_as_float(v0 << 16);
            ay0 += e0 * __uint_as_float(v0 & 0xffff0000u);
        }
    }

    const float inv = 1.f / (den + EPS);
    const float2 bv = ((const float2*)bias)[lane];
    float2 o;
    o.x = ((ax0 + ax1) + (ax2 + ax3)) * inv + bv.x;
    o.y = ((ay0 + ay1) + (ay2 + ay3)) * inv + bv.y;
    ((float2*)out)[(size_t)n * 64 + lane] = o;
}

// ---------------- launch ----------------
extern "C" void kernel_launch(void* const* d_in, const int* in_sizes, int n_in,
                              void* d_out, int out_size, void* d_ws, size_t ws_size,
                              hipStream_t stream)
{
    const float* x     = (const float*)d_in[0];
    const int*   ei    = (const int*)d_in[1];
    const float* w     = (const float*)d_in[2];
    const float* att_s = (const float*)d_in[3];
    const float* att_d = (const float*)d_in[4];
    const float* bias  = (const float*)d_in[5];
    float* out = (float*)d_out;

    const int N = in_sizes[0] / IN_CH;
    const int E = in_sizes[1] / 2;
    const int* src = ei;
    const int* dst = ei + E;

    char* p = (char*)d_ws;
    auto take = [&](size_t bytes) { char* q = p; p += (bytes + 255) & ~size_t(255); return q; };
    unsigned short* xpb = (unsigned short*)take((size_t)N * OUT_CH * 2);
    unsigned short* wt  = (unsigned short*)take((size_t)OUT_CH * IN_CH * 2);
    float* asrc   = (float*)take((size_t)N * 4);
    float* adst   = (float*)take((size_t)N * 4);
    int*   deg    = (int*)take((size_t)N * 4);
    int*   row_ptr= (int*)take((size_t)(N + 1) * 4);
    int*   bsum   = (int*)take(SCAN_NB * 4);
    int*   boff   = (int*)take(SCAN_NB * 4);
    int*   pw     = (int*)take((size_t)E * 4);
    int*   col    = (int*)take((size_t)E * 4);

    hipMemsetAsync(deg, 0, (size_t)N * 4, stream);
    convert_w_kernel<<<OUT_CH, IN_CH, 0, stream>>>(w, wt);

    const int gemm_blocks = (N + 63) / 64;
    const int hist_blocks = (E + 256 * 8 - 1) / (256 * 8);
    fused_gemm_hist_kernel<<<hist_blocks + gemm_blocks, 256, 0, stream>>>(
        x, wt, att_s, att_d, xpb, asrc, adst, N,
        src, dst, deg, pw, E, hist_blocks);

    scan_partial_kernel<<<SCAN_NB, SCAN_NT, 0, stream>>>(deg, bsum, N);
    scan_blocksums_kernel<<<1, SCAN_NB, 0, stream>>>(bsum, boff, row_ptr, N);
    scan_fill_kernel<<<SCAN_NB, SCAN_NT, 0, stream>>>(deg, boff, row_ptr, N);

    const int sc_blocks = (E + 256 * 8 - 1) / (256 * 8);
    scatter_kernel<<<sc_blocks, 256, 0, stream>>>(src, dst, row_ptr, pw, col, E, sc_blocks);

    aggregate_kernel<<<(N + 3) / 4, 256, 0, stream>>>(
        xpb, asrc, adst, row_ptr, col, bias, out, N);
}